// Round 3
// baseline (1033.339 us; speedup 1.0000x reference)
//
#include <hip/hip_runtime.h>
#include <cstdint>

using short8  = __attribute__((ext_vector_type(8))) short;
using floatx4 = __attribute__((ext_vector_type(4))) float;

__device__ __forceinline__ unsigned short f2bf(float x){
  union { float f; unsigned u; } v; v.f = x;
  unsigned r = v.u + 0x7fffu + ((v.u >> 16) & 1u);
  return (unsigned short)(r >> 16);
}

__device__ __forceinline__ float eluf(float v){ return v > 0.f ? v : expm1f(v); }

__device__ __forceinline__ void ld_g2l16(const void* g, void* l){
  __builtin_amdgcn_global_load_lds(
      (const __attribute__((address_space(1))) void*)g,
      (__attribute__((address_space(3))) void*)l, 16, 0, 0);
}

// ---------------- prep: 5 weight transposes (f32->bf16) + zero deg/cnt -----
__device__ __forceinline__ void tcv(const float* W, unsigned short* Wt, int K, int Nc, int i){
  int n = i / K, k = i - n * K;
  Wt[i] = f2bf(W[(size_t)k * Nc + n]);
}
__global__ void k_prep(const float* __restrict__ w0, const float* __restrict__ w1,
                       const float* __restrict__ w2, const float* __restrict__ c1w,
                       const float* __restrict__ c2w,
                       unsigned short* __restrict__ w0t, unsigned short* __restrict__ w1t,
                       unsigned short* __restrict__ w2t, unsigned short* __restrict__ c1wt,
                       unsigned short* __restrict__ c2wt,
                       int* __restrict__ degi, int* __restrict__ cnt, int N){
  int idx = blockIdx.x * 256 + threadIdx.x;
  if (idx < 524288){ tcv(w0, w0t, 1024, 512, idx); return; }
  idx -= 524288;
  if (idx < 65536){ tcv(w1, w1t, 512, 128, idx); return; }
  idx -= 65536;
  if (idx < 8192){ tcv(w2, w2t, 128, 64, idx); return; }
  idx -= 8192;
  if (idx < 2048){ tcv(c1w, c1wt, 64, 32, idx); return; }
  idx -= 2048;
  if (idx < 512){ tcv(c2w, c2wt, 32, 16, idx); return; }
  idx -= 512;
  if (idx < N){ degi[idx] = 0; return; }
  idx -= N;
  if (idx < N){ cnt[idx] = 0; }
}

// ---------------- maxpool(2) + layernorm(1024) -> bf16 ---------------------
__global__ __launch_bounds__(256) void k_pool_ln(const float* __restrict__ x,
    const float* __restrict__ g, const float* __restrict__ b,
    unsigned short* __restrict__ h0){
  const int i = blockIdx.x, t = threadIdx.x;
  const float4* xr = (const float4*)(x + (size_t)i * 2048);
  float4 va = xr[2 * t], vb = xr[2 * t + 1];
  float v0 = fmaxf(va.x, va.y), v1 = fmaxf(va.z, va.w);
  float v2 = fmaxf(vb.x, vb.y), v3 = fmaxf(vb.z, vb.w);
  float s  = v0 + v1 + v2 + v3;
  float s2 = v0*v0 + v1*v1 + v2*v2 + v3*v3;
  #pragma unroll
  for (int off = 32; off > 0; off >>= 1){
    s  += __shfl_down(s, off);
    s2 += __shfl_down(s2, off);
  }
  __shared__ float ps[4], ps2[4];
  int w = t >> 6;
  if ((t & 63) == 0){ ps[w] = s; ps2[w] = s2; }
  __syncthreads();
  float S  = ps[0] + ps[1] + ps[2] + ps[3];
  float S2 = ps2[0] + ps2[1] + ps2[2] + ps2[3];
  float mu   = S * (1.f / 1024.f);
  float var  = S2 * (1.f / 1024.f) - mu * mu;
  float rstd = rsqrtf(var + 1e-5f);
  float4 g4 = ((const float4*)g)[t];
  float4 b4 = ((const float4*)b)[t];
  ushort4 o;
  o.x = f2bf((v0 - mu) * rstd * g4.x + b4.x);
  o.y = f2bf((v1 - mu) * rstd * g4.y + b4.y);
  o.z = f2bf((v2 - mu) * rstd * g4.z + b4.z);
  o.w = f2bf((v3 - mu) * rstd * g4.w + b4.w);
  *(ushort4*)(h0 + (size_t)i * 1024 + t * 4) = o;
}

// ---------------- MFMA GEMM: C = elu(A@B + bias) -> bf16 (gemm1) ----------
__global__ __launch_bounds__(256) void k_gemm(const unsigned short* __restrict__ A,
    const unsigned short* __restrict__ Bt, const float* __restrict__ bias,
    unsigned short* __restrict__ C, int M, int K, int N){
  __shared__ __align__(16) unsigned short lA[128 * 64];
  __shared__ __align__(16) unsigned short lB[128 * 64];
  const int tid  = threadIdx.x;
  const int lane = tid & 63;
  const int w    = tid >> 6;
  const int wm = w >> 1, wn = w & 1;
  const int m0 = blockIdx.x * 128;
  const int n0 = blockIdx.y * 128;
  const int q = lane >> 4, ml = lane & 15;
  floatx4 acc[4][4] = {};
  const int nKB = K >> 6;
  for (int kb = 0; kb < nKB; ++kb){
    #pragma unroll
    for (int i = 0; i < 4; ++i){
      int cpos = (w * 4 + i) * 64 + lane;
      int row  = cpos >> 3;
      int p    = cpos & 7;
      int cc   = p ^ (row & 7);
      int ar   = m0 + row; ar = ar < M ? ar : M - 1;
      ld_g2l16(A  + (size_t)ar        * K + (kb * 64 + cc * 8), &lA[(w * 4 + i) * 512]);
      ld_g2l16(Bt + (size_t)(n0 + row) * K + (kb * 64 + cc * 8), &lB[(w * 4 + i) * 512]);
    }
    __syncthreads();
    #pragma unroll
    for (int kk = 0; kk < 2; ++kk){
      short8 af[4], bfr[4];
      #pragma unroll
      for (int mi = 0; mi < 4; ++mi){
        int row = wm * 64 + mi * 16 + ml;
        int p   = (kk * 4 + q) ^ (row & 7);
        af[mi] = *(const short8*)&lA[row * 64 + p * 8];
      }
      #pragma unroll
      for (int ni = 0; ni < 4; ++ni){
        int row = wn * 64 + ni * 16 + ml;
        int p   = (kk * 4 + q) ^ (row & 7);
        bfr[ni] = *(const short8*)&lB[row * 64 + p * 8];
      }
      #pragma unroll
      for (int mi = 0; mi < 4; ++mi)
        #pragma unroll
        for (int ni = 0; ni < 4; ++ni)
          acc[mi][ni] = __builtin_amdgcn_mfma_f32_16x16x32_bf16(af[mi], bfr[ni], acc[mi][ni], 0, 0, 0);
    }
    __syncthreads();
  }
  #pragma unroll
  for (int mi = 0; mi < 4; ++mi){
    #pragma unroll
    for (int ni = 0; ni < 4; ++ni){
      int gc = n0 + wn * 64 + ni * 16 + ml;
      float bv = bias[gc];
      #pragma unroll
      for (int r = 0; r < 4; ++r){
        int gr = m0 + wm * 64 + mi * 16 + q * 4 + r;
        if (gr < M){
          float v = acc[mi][ni][r] + bv;
          v = v > 0.f ? v : expm1f(v);
          C[(size_t)gr * N + gc] = f2bf(v);
        }
      }
    }
  }
}

// ------- fused: h2 = elu(h1@w1+b1); h3 = elu(h2@w2+b2); xs1 = (h3@c1w)*dinv
// h1: Mx512 bf16. Per block: 128 rows, full width. h2/h3 live only in LDS.
#define H2S 136   // padded stride (ushorts) for 128-col h2 tile
#define H3S 72    // padded stride for 64-col h3 tile
__global__ __launch_bounds__(256) void k_mlp2(const unsigned short* __restrict__ h1,
    const unsigned short* __restrict__ w1t, const float* __restrict__ b1,
    const unsigned short* __restrict__ w2t, const float* __restrict__ b2,
    const unsigned short* __restrict__ c1wt, const float* __restrict__ dinv,
    float* __restrict__ xs1, int M){
  __shared__ __align__(16) unsigned short sm[128 * H2S + 128 * H3S];
  unsigned short* lA  = sm;            // 8192 (staging, overlaid on h2s)
  unsigned short* lB  = sm + 8192;     // 8192
  unsigned short* h2s = sm;            // 128 x H2S
  unsigned short* h3s = sm + 128 * H2S;// 128 x H3S
  const int tid  = threadIdx.x;
  const int lane = tid & 63;
  const int w    = tid >> 6;
  const int wm = w >> 1, wn = w & 1;
  const int m0 = blockIdx.x * 128;
  const int q = lane >> 4, ml = lane & 15;
  floatx4 acc[4][4] = {};
  // ---- GEMM: h1(128x512) @ w1t -> 128x128
  for (int kb = 0; kb < 8; ++kb){
    #pragma unroll
    for (int i = 0; i < 4; ++i){
      int cpos = (w * 4 + i) * 64 + lane;
      int row  = cpos >> 3;
      int p    = cpos & 7;
      int cc   = p ^ (row & 7);
      int ar   = m0 + row; ar = ar < M ? ar : M - 1;
      ld_g2l16(h1  + (size_t)ar  * 512 + (kb * 64 + cc * 8), &lA[(w * 4 + i) * 512]);
      ld_g2l16(w1t + (size_t)row * 512 + (kb * 64 + cc * 8), &lB[(w * 4 + i) * 512]);
    }
    __syncthreads();
    #pragma unroll
    for (int kk = 0; kk < 2; ++kk){
      short8 af[4], bfr[4];
      #pragma unroll
      for (int mi = 0; mi < 4; ++mi){
        int row = wm * 64 + mi * 16 + ml;
        int p   = (kk * 4 + q) ^ (row & 7);
        af[mi] = *(const short8*)&lA[row * 64 + p * 8];
      }
      #pragma unroll
      for (int ni = 0; ni < 4; ++ni){
        int row = wn * 64 + ni * 16 + ml;
        int p   = (kk * 4 + q) ^ (row & 7);
        bfr[ni] = *(const short8*)&lB[row * 64 + p * 8];
      }
      #pragma unroll
      for (int mi = 0; mi < 4; ++mi)
        #pragma unroll
        for (int ni = 0; ni < 4; ++ni)
          acc[mi][ni] = __builtin_amdgcn_mfma_f32_16x16x32_bf16(af[mi], bfr[ni], acc[mi][ni], 0, 0, 0);
    }
    __syncthreads();
  }
  // ---- h2 tile -> LDS (bf16, elu+bias)
  #pragma unroll
  for (int mi = 0; mi < 4; ++mi){
    #pragma unroll
    for (int ni = 0; ni < 4; ++ni){
      int col = wn * 64 + ni * 16 + ml;
      float bv = b1[col];
      #pragma unroll
      for (int r = 0; r < 4; ++r){
        int row = wm * 64 + mi * 16 + q * 4 + r;
        h2s[row * H2S + col] = f2bf(eluf(acc[mi][ni][r] + bv));
      }
    }
  }
  __syncthreads();
  // ---- h3 = elu(h2 @ w2 + b2): per-wave rows r0..r0+31, K=128, N=64
  const int r0 = w * 32;
  floatx4 acc3[2][4] = {};
  #pragma unroll
  for (int kk = 0; kk < 4; ++kk){
    short8 a3[2];
    #pragma unroll
    for (int mi = 0; mi < 2; ++mi)
      a3[mi] = *(const short8*)&h2s[(r0 + mi * 16 + ml) * H2S + kk * 32 + q * 8];
    #pragma unroll
    for (int ni = 0; ni < 4; ++ni){
      short8 b3 = *(const short8*)&w2t[(ni * 16 + ml) * 128 + kk * 32 + q * 8];
      #pragma unroll
      for (int mi = 0; mi < 2; ++mi)
        acc3[mi][ni] = __builtin_amdgcn_mfma_f32_16x16x32_bf16(a3[mi], b3, acc3[mi][ni], 0, 0, 0);
    }
  }
  #pragma unroll
  for (int mi = 0; mi < 2; ++mi){
    #pragma unroll
    for (int ni = 0; ni < 4; ++ni){
      int col = ni * 16 + ml;
      float bv = b2[col];
      #pragma unroll
      for (int r = 0; r < 4; ++r){
        int row = r0 + mi * 16 + q * 4 + r;
        h3s[row * H3S + col] = f2bf(eluf(acc3[mi][ni][r] + bv));
      }
    }
  }
  __syncthreads();
  // ---- xs1 = (h3 @ c1w) * dinv: K=64, N=32
  floatx4 accx[2][2] = {};
  #pragma unroll
  for (int kk = 0; kk < 2; ++kk){
    short8 ax[2];
    #pragma unroll
    for (int mi = 0; mi < 2; ++mi)
      ax[mi] = *(const short8*)&h3s[(r0 + mi * 16 + ml) * H3S + kk * 32 + q * 8];
    #pragma unroll
    for (int ni = 0; ni < 2; ++ni){
      short8 bx = *(const short8*)&c1wt[(ni * 16 + ml) * 64 + kk * 32 + q * 8];
      #pragma unroll
      for (int mi = 0; mi < 2; ++mi)
        accx[mi][ni] = __builtin_amdgcn_mfma_f32_16x16x32_bf16(ax[mi], bx, accx[mi][ni], 0, 0, 0);
    }
  }
  #pragma unroll
  for (int mi = 0; mi < 2; ++mi){
    #pragma unroll
    for (int ni = 0; ni < 2; ++ni){
      int col = ni * 16 + ml;
      #pragma unroll
      for (int r = 0; r < 4; ++r){
        int gr = m0 + r0 + mi * 16 + q * 4 + r;
        if (gr < M) xs1[(size_t)gr * 32 + col] = accx[mi][ni][r] * dinv[gr];
      }
    }
  }
}

// ---------------- CSR build ------------------------------------------------
__global__ void k_degi(const int* __restrict__ ei, int* __restrict__ deg, int E){
  int e = blockIdx.x * 256 + threadIdx.x;
  if (e < E) atomicAdd(&deg[ei[E + e]], 1);
}
__global__ __launch_bounds__(256) void k_scan1(const int* __restrict__ deg,
    int* __restrict__ ptr, int* __restrict__ btot, float* __restrict__ dinv, int Nn){
  __shared__ int s[256];
  int b = blockIdx.x, t = threadIdx.x, i = b * 256 + t;
  int v = (i < Nn) ? deg[i] : 0;
  if (i < Nn) dinv[i] = rsqrtf((float)v + 1.0f);
  s[t] = v; __syncthreads();
  #pragma unroll
  for (int off = 1; off < 256; off <<= 1){
    int x = (t >= off) ? s[t - off] : 0;
    __syncthreads();
    s[t] += x; __syncthreads();
  }
  if (i < Nn) ptr[i] = s[t] - v;
  if (t == 255) btot[b] = s[255];
}
__global__ __launch_bounds__(256) void k_scan2(int* __restrict__ btot, int nb){
  __shared__ int s[256];
  int t = threadIdx.x;
  int v = (t < nb) ? btot[t] : 0;
  s[t] = v; __syncthreads();
  #pragma unroll
  for (int off = 1; off < 256; off <<= 1){
    int x = (t >= off) ? s[t - off] : 0;
    __syncthreads();
    s[t] += x; __syncthreads();
  }
  if (t < nb) btot[t] = s[t] - v;
}
__global__ void k_scan3(int* __restrict__ ptr, const int* __restrict__ btot, int Nn){
  int i = blockIdx.x * 256 + threadIdx.x;
  if (i < Nn) ptr[i] += btot[i >> 8];
}
__global__ void k_fill(const int* __restrict__ ei, const int* __restrict__ ptr,
                       int* __restrict__ cnt, int* __restrict__ csr, int E){
  int e = blockIdx.x * 256 + threadIdx.x;
  if (e >= E) return;
  int d = ei[E + e];
  int pos = ptr[d] + atomicAdd(&cnt[d], 1);
  csr[pos] = ei[e];
}

// ---- gather1 + fin1: acc=xs1[d]+sum nbrs; h4=elu(dinv*acc+c1b); xs2=(h4@c2w)*dinv
__global__ __launch_bounds__(256) void k_gather1(const int* __restrict__ csr,
    const int* __restrict__ ptr, const int* __restrict__ deg,
    const float* __restrict__ xs1, const float* __restrict__ c1b,
    const float* __restrict__ c2w, const float* __restrict__ dinv,
    float* __restrict__ xs2, int M){
  int wid = (blockIdx.x * 256 + threadIdx.x) >> 6;
  if (wid >= M) return;
  int lane = threadIdx.x & 63;
  int g = lane >> 3, c = lane & 7;            // 8 edges in flight x 8 float4-cols
  int start = ptr[wid], n = deg[wid];
  float4 a = {0.f, 0.f, 0.f, 0.f};
  for (int j = g; j < n; j += 8){
    int s = csr[start + j];
    float4 v = *(const float4*)&xs1[(size_t)s * 32 + c * 4];
    a.x += v.x; a.y += v.y; a.z += v.z; a.w += v.w;
  }
  #pragma unroll
  for (int off = 8; off < 64; off <<= 1){
    a.x += __shfl_xor(a.x, off);
    a.y += __shfl_xor(a.y, off);
    a.z += __shfl_xor(a.z, off);
    a.w += __shfl_xor(a.w, off);
  }
  float4 self = *(const float4*)&xs1[(size_t)wid * 32 + c * 4];
  a.x += self.x; a.y += self.y; a.z += self.z; a.w += self.w;
  float dv = dinv[wid];
  float h4[4];
  h4[0] = eluf(dv * a.x + c1b[c * 4 + 0]);
  h4[1] = eluf(dv * a.y + c1b[c * 4 + 1]);
  h4[2] = eluf(dv * a.z + c1b[c * 4 + 2]);
  h4[3] = eluf(dv * a.w + c1b[c * 4 + 3]);
  float p[16];
  #pragma unroll
  for (int j = 0; j < 16; ++j) p[j] = 0.f;
  #pragma unroll
  for (int u = 0; u < 4; ++u){
    const float4* wr = (const float4*)&c2w[(c * 4 + u) * 16];
    #pragma unroll
    for (int j4 = 0; j4 < 4; ++j4){
      float4 wv = wr[j4];
      p[j4 * 4 + 0] += h4[u] * wv.x;
      p[j4 * 4 + 1] += h4[u] * wv.y;
      p[j4 * 4 + 2] += h4[u] * wv.z;
      p[j4 * 4 + 3] += h4[u] * wv.w;
    }
  }
  #pragma unroll
  for (int off = 1; off < 8; off <<= 1)
    #pragma unroll
    for (int j = 0; j < 16; ++j) p[j] += __shfl_xor(p[j], off);
  if (lane == 0){
    float4* po = (float4*)&xs2[(size_t)wid * 16];
    #pragma unroll
    for (int j4 = 0; j4 < 4; ++j4){
      float4 v = {dv * p[j4*4+0], dv * p[j4*4+1], dv * p[j4*4+2], dv * p[j4*4+3]};
      po[j4] = v;
    }
  }
}

// ---- gather2 + fin2: z = dinv*(xs2[d]+sum nbrs) + c2b ---------------------
__global__ __launch_bounds__(256) void k_gather2(const int* __restrict__ csr,
    const int* __restrict__ ptr, const int* __restrict__ deg,
    const float* __restrict__ xs2, const float* __restrict__ c2b,
    const float* __restrict__ dinv, float* __restrict__ z, int M){
  int wid = (blockIdx.x * 256 + threadIdx.x) >> 6;
  if (wid >= M) return;
  int lane = threadIdx.x & 63;
  int g = lane >> 2, c = lane & 3;            // 16 edges in flight x 4 float4-cols
  int start = ptr[wid], n = deg[wid];
  float4 a = {0.f, 0.f, 0.f, 0.f};
  for (int j = g; j < n; j += 16){
    int s = csr[start + j];
    float4 v = *(const float4*)&xs2[(size_t)s * 16 + c * 4];
    a.x += v.x; a.y += v.y; a.z += v.z; a.w += v.w;
  }
  #pragma unroll
  for (int off = 4; off < 64; off <<= 1){
    a.x += __shfl_xor(a.x, off);
    a.y += __shfl_xor(a.y, off);
    a.z += __shfl_xor(a.z, off);
    a.w += __shfl_xor(a.w, off);
  }
  if (g == 0){
    float4 self = *(const float4*)&xs2[(size_t)wid * 16 + c * 4];
    float dv = dinv[wid];
    const float4 cb = ((const float4*)c2b)[c];
    float4 o = {dv * (a.x + self.x) + cb.x, dv * (a.y + self.y) + cb.y,
                dv * (a.z + self.z) + cb.z, dv * (a.w + self.w) + cb.w};
    *(float4*)&z[(size_t)wid * 16 + c * 4] = o;
  }
}

// ---------------- edge head MLP --------------------------------------------
__global__ __launch_bounds__(256) void k_edge(const int* __restrict__ ei,
    const int* __restrict__ mask, const float* __restrict__ z,
    const float* __restrict__ lw1, const float* __restrict__ lb1,
    const float* __restrict__ lw2, const float* __restrict__ lb2,
    float* __restrict__ out, int nsel, int E){
  __shared__ float w1s[512], b1s[16], w2s[32], b2s[2];
  int t = threadIdx.x;
  for (int idx = t; idx < 512; idx += 256) w1s[idx] = lw1[idx];
  if (t < 16) b1s[t] = lb1[t];
  if (t < 32) w2s[t] = lw2[t];
  if (t < 2)  b2s[t] = lb2[t];
  __syncthreads();
  int j = blockIdx.x * 256 + t;
  if (j >= nsel) return;
  int m = mask[j];
  int s = ei[m], d = ei[E + m];
  float e[32];
  const float4* zs = (const float4*)(z + (size_t)s * 16);
  const float4* zd = (const float4*)(z + (size_t)d * 16);
  #pragma unroll
  for (int k4 = 0; k4 < 4; ++k4){
    float4 v = zs[k4];
    e[k4 * 4 + 0] = v.x; e[k4 * 4 + 1] = v.y; e[k4 * 4 + 2] = v.z; e[k4 * 4 + 3] = v.w;
  }
  #pragma unroll
  for (int k4 = 0; k4 < 4; ++k4){
    float4 v = zd[k4];
    e[16 + k4 * 4 + 0] = v.x; e[16 + k4 * 4 + 1] = v.y;
    e[16 + k4 * 4 + 2] = v.z; e[16 + k4 * 4 + 3] = v.w;
  }
  float o[16];
  #pragma unroll
  for (int oo = 0; oo < 16; ++oo){
    float acc = b1s[oo];
    #pragma unroll
    for (int ii = 0; ii < 32; ++ii) acc += e[ii] * w1s[ii * 16 + oo];
    o[oo] = eluf(acc);
  }
  float r0 = b2s[0], r1 = b2s[1];
  #pragma unroll
  for (int oo = 0; oo < 16; ++oo){ r0 += o[oo] * w2s[oo * 2]; r1 += o[oo] * w2s[oo * 2 + 1]; }
  out[(size_t)j * 2]     = r0;
  out[(size_t)j * 2 + 1] = r1;
}

extern "C" void kernel_launch(void* const* d_in, const int* in_sizes, int n_in,
                              void* d_out, int out_size, void* d_ws, size_t ws_size,
                              hipStream_t stream){
  const float* x    = (const float*)d_in[0];
  const int*   ei   = (const int*)d_in[1];
  const int*   mask = (const int*)d_in[2];
  const float* ln_g = (const float*)d_in[3];
  const float* ln_b = (const float*)d_in[4];
  const float* w0   = (const float*)d_in[5];
  const float* b0   = (const float*)d_in[6];
  const float* w1   = (const float*)d_in[7];
  const float* b1   = (const float*)d_in[8];
  const float* w2   = (const float*)d_in[9];
  const float* b2   = (const float*)d_in[10];
  const float* c1w  = (const float*)d_in[11];
  const float* c1b  = (const float*)d_in[12];
  const float* c2w  = (const float*)d_in[13];
  const float* c2b  = (const float*)d_in[14];
  const float* lw1  = (const float*)d_in[15];
  const float* lb1  = (const float*)d_in[16];
  const float* lw2  = (const float*)d_in[17];
  const float* lb2  = (const float*)d_in[18];
  float* out = (float*)d_out;

  const int N    = in_sizes[0] / 2048;
  const int E    = in_sizes[1] / 2;
  const int NSEL = in_sizes[2];
  const int NB   = (N + 255) / 256;

  // ---- workspace layout (no aliasing) ----
  char* ws = (char*)d_ws;
  size_t o = 0;
  unsigned short* h0   = (unsigned short*)(ws + o); o += (size_t)N * 1024 * 2;
  unsigned short* h1   = (unsigned short*)(ws + o); o += (size_t)N * 512 * 2;
  unsigned short* w0t  = (unsigned short*)(ws + o); o += 1024 * 512 * 2;
  unsigned short* w1t  = (unsigned short*)(ws + o); o += 512 * 128 * 2;
  unsigned short* w2t  = (unsigned short*)(ws + o); o += 128 * 64 * 2;
  unsigned short* c1wt = (unsigned short*)(ws + o); o += 64 * 32 * 2;
  unsigned short* c2wt = (unsigned short*)(ws + o); o += 32 * 16 * 2;
  int*   degi = (int*)(ws + o);   o += (size_t)N * 4;
  int*   cnt  = (int*)(ws + o);   o += (size_t)N * 4;
  int*   ptr  = (int*)(ws + o);   o += (size_t)N * 4;
  float* dinv = (float*)(ws + o); o += (size_t)N * 4;
  int*   btot = (int*)(ws + o);   o += 256 * 4;
  int*   csr  = (int*)(ws + o);   o += (size_t)E * 4;
  float* xs1  = (float*)(ws + o); o += (size_t)N * 32 * 4;
  float* xs2  = (float*)(ws + o); o += (size_t)N * 16 * 4;
  float* z    = (float*)(ws + o); o += (size_t)N * 16 * 4;

  // 1. prep: weight transposes + zero degi/cnt
  int prep_n = 524288 + 65536 + 8192 + 2048 + 512 + 2 * N;
  k_prep<<<(prep_n + 255) / 256, 256, 0, stream>>>(w0, w1, w2, c1w, c2w,
      w0t, w1t, w2t, c1wt, c2wt, degi, cnt, N);
  // 2. maxpool + layernorm -> h0
  k_pool_ln<<<N, 256, 0, stream>>>(x, ln_g, ln_b, h0);
  // 3. GEMM1: h1 = elu(h0 @ w0 + b0)
  k_gemm<<<dim3((N + 127) / 128, 4), 256, 0, stream>>>(h0, w0t, b0, h1, N, 1024, 512);
  // 4-8. CSR build + dinv
  k_degi<<<(E + 255) / 256, 256, 0, stream>>>(ei, degi, E);
  k_scan1<<<NB, 256, 0, stream>>>(degi, ptr, btot, dinv, N);
  k_scan2<<<1, 256, 0, stream>>>(btot, NB);
  k_scan3<<<NB, 256, 0, stream>>>(ptr, btot, N);
  k_fill<<<(E + 255) / 256, 256, 0, stream>>>(ei, ptr, cnt, csr, E);
  // 9. fused MLP: h1 -> xs1 (h2,h3 in LDS only)
  k_mlp2<<<(N + 127) / 128, 256, 0, stream>>>(h1, w1t, b1, w2t, b2, c1wt, dinv, xs1, N);
  // 10. conv1 gather + fin1 -> xs2
  k_gather1<<<(N + 3) / 4, 256, 0, stream>>>(csr, ptr, degi, xs1, c1b, c2w, dinv, xs2, N);
  // 11. conv2 gather + fin2 -> z
  k_gather2<<<(N + 3) / 4, 256, 0, stream>>>(csr, ptr, degi, xs2, c2b, dinv, z, N);
  // 12. edge head
  k_edge<<<(NSEL + 255) / 256, 256, 0, stream>>>(ei, mask, z, lw1, lb1, lw2, lb2,
                                                 out, NSEL, E);
}